// Round 7
// baseline (317.542 us; speedup 1.0000x reference)
//
#include <hip/hip_runtime.h>

typedef unsigned short u16;
typedef __attribute__((ext_vector_type(8))) short short8;
typedef __attribute__((ext_vector_type(4))) float f32x4;

__device__ __forceinline__ u16 f2bf(float f) {
  unsigned u = __builtin_bit_cast(unsigned, f);
  u += 0x7FFFu + ((u >> 16) & 1u);
  return (u16)(u >> 16);
}
__device__ __forceinline__ float bf2f(u16 s) {
  unsigned u = ((unsigned)s) << 16;
  return __builtin_bit_cast(float, u);
}
__device__ __forceinline__ void gll16(const u16* g, u16* l) {
  __builtin_amdgcn_global_load_lds(
      (const __attribute__((address_space(1))) void*)g,
      (__attribute__((address_space(3))) void*)l, 16, 0, 0);
}

// ---------------- convert f32 -> bf16 (vectorized) ----------------
__global__ __launch_bounds__(256) void convert_f32_bf16(
    const float* __restrict__ in, u16* __restrict__ out, int n4) {
  int i = blockIdx.x * 256 + threadIdx.x;
  if (i >= n4) return;
  float4 v = ((const float4*)in)[i];
  ushort4 o;
  o.x = f2bf(v.x); o.y = f2bf(v.y); o.z = f2bf(v.z); o.w = f2bf(v.w);
  ((ushort4*)out)[i] = o;
}

// ---------------- transpose f32[R][C] -> bf16[C][R] ----------------
__global__ __launch_bounds__(256) void transpose_f32_bf16(
    const float* __restrict__ in, u16* __restrict__ out, int R, int C) {
  __shared__ float tile[32][33];
  int c0 = blockIdx.x * 32, r0 = blockIdx.y * 32;
  int tx = threadIdx.x, ty = threadIdx.y;
  #pragma unroll
  for (int i = 0; i < 32; i += 8)
    tile[ty + i][tx] = in[(size_t)(r0 + ty + i) * C + c0 + tx];
  __syncthreads();
  #pragma unroll
  for (int i = 0; i < 32; i += 8)
    out[(size_t)(c0 + ty + i) * R + r0 + tx] = f2bf(tile[tx][ty + i]);
}

// ---------------- 128x128 bf16 MFMA GEMM, BK=64, swizzled LDS ----------------
// LDS dest linear (global_load_lds requirement); global SOURCE slot pre-permuted
// (slot^row&7 within the same 128B row -> coalescing intact); ds_read applies the
// same XOR. Rule #21: both-sides swizzle. 8 gll16/wave stages the full 32KB tile:
// part p covers rows p*32 + w*8 + (lane>>3) of both Al and Bl.
template<int MODE>
__global__ __launch_bounds__(256) void gemm_gll(
    const u16* __restrict__ A, const u16* __restrict__ Bt, int M, int NT,
    const float* __restrict__ bias, u16* __restrict__ ob, float* __restrict__ of) {
  constexpr int K = 768;
  __shared__ __align__(16) u16 Al[128 * 64];
  __shared__ __align__(16) u16 Bl[128 * 64];
  int tid = threadIdx.x, lane = tid & 63, w = tid >> 6;
  // bijective XCD remap (m204), m-major tiles (n-fastest within an XCD chunk)
  int nwg = gridDim.x, orig = blockIdx.x;
  int q = nwg >> 3, r = nwg & 7, xcd = orig & 7, slot = orig >> 3;
  int wg = (xcd < r ? xcd * (q + 1) : r * (q + 1) + (xcd - r) * q) + slot;
  int mt = wg / NT, nt = wg - mt * NT;
  int m0 = mt * 128, n0 = nt * 128;
  int wm = w >> 1, wn = w & 1;
  int lq = lane & 15, oct = lane >> 4;
  // staging: row-local = p*32 + w*8 + (lane>>3); 16B-slot = lane&7, pre-swizzled.
  int srow = w * 8 + (lane >> 3);
  int sslot = (lane & 7) ^ (lane >> 3);
  const u16* gA[4];
  const u16* gB[4];
  #pragma unroll
  for (int p = 0; p < 4; ++p) {
    int ar = m0 + p * 32 + srow; if (ar > M - 1) ar = M - 1;
    gA[p] = A + (size_t)ar * K + sslot * 8;
    gB[p] = Bt + (size_t)(n0 + p * 32 + srow) * K + sslot * 8;
  }
  f32x4 acc[4][4] = {};
  for (int kt = 0; kt < K; kt += 64) {
    #pragma unroll
    for (int p = 0; p < 4; ++p) {
      gll16(gA[p] + kt, Al + p * 2048 + w * 512);
      gll16(gB[p] + kt, Bl + p * 2048 + w * 512);
    }
    __syncthreads();   // vmcnt(0) drain + barrier
    #pragma unroll
    for (int ks = 0; ks < 2; ++ks) {
      short8 af[4], bq[4];
      int rslot = ((ks * 4 + oct) ^ (lq & 7)) * 8;
      #pragma unroll
      for (int i = 0; i < 4; ++i)
        af[i] = *(const short8*)(Al + (wm * 64 + i * 16 + lq) * 64 + rslot);
      #pragma unroll
      for (int j = 0; j < 4; ++j)
        bq[j] = *(const short8*)(Bl + (wn * 64 + j * 16 + lq) * 64 + rslot);
      #pragma unroll
      for (int i = 0; i < 4; ++i)
        #pragma unroll
        for (int j = 0; j < 4; ++j)
          acc[i][j] = __builtin_amdgcn_mfma_f32_16x16x32_bf16(af[i], bq[j], acc[i][j], 0, 0, 0);
    }
    __syncthreads();   // protect LDS before next stage
  }
  int ldc = NT * 128;
  float bs[4];
  #pragma unroll
  for (int j = 0; j < 4; ++j) bs[j] = bias[n0 + wn * 64 + j * 16 + lq];
  #pragma unroll
  for (int i = 0; i < 4; ++i) {
    #pragma unroll
    for (int rr = 0; rr < 4; ++rr) {
      int m = m0 + wm * 64 + i * 16 + oct * 4 + rr;
      if (m < M) {
        #pragma unroll
        for (int j = 0; j < 4; ++j) {
          int c = n0 + wn * 64 + j * 16 + lq;
          float val = acc[i][j][rr] + bs[j];
          if (MODE == 0) ob[(size_t)m * ldc + c] = f2bf(val);
          else           of[(size_t)m * ldc + c] = val;
        }
      }
    }
  }
}

// ---------------- SAVE aggregation, fused q/k/v, 12-point stencil ----------------
__global__ __launch_bounds__(256) void save_agg_fused(
    const u16* __restrict__ in, u16* __restrict__ q2, u16* __restrict__ k2,
    u16* __restrict__ v2, const float* __restrict__ wq,
    const float* __restrict__ wk, const float* __restrict__ wv) {
  constexpr int PER = 768 * 197 * 8;
  int vid = blockIdx.x * 256 + threadIdx.x;
  if (vid >= 3 * PER) return;
  int which = vid / PER;
  int rem = vid - which * PER;
  int dv = rem & 7;
  int n = (rem >> 3) % 197;
  int bh = rem / (197 * 8);
  int b = bh / 12, h = bh - b * 12;
  const float* w = (which == 0) ? wq : (which == 1) ? wk : wv;
  u16* outp = (which == 0) ? q2 : (which == 1) ? k2 : v2;
  size_t colbase = (size_t)which * 768 + h * 64 + dv * 8;
  const u16* rowp = in + (size_t)b * 197 * 2304 + colbase;
  size_t rowoff_out = ((size_t)bh * 197 + n) * 64 + dv * 8;
  uint4 cu = *(const uint4*)(rowp + (size_t)n * 2304);
  if (n == 0) { *(uint4*)(outp + rowoff_out) = cu; return; }
  union V8 { uint4 u; u16 s[8]; };
  V8 cv; cv.u = cu;
  float acc[8];
  #pragma unroll
  for (int j = 0; j < 8; ++j) acc[j] = bf2f(cv.s[j]);
  int rank = n - 1;
  int rw = rank % 14;
  const float dist[3] = {0.93941306281347579f, 0.77880078307140487f, 0.56978282473092302f};
  auto add = [&](int ntok, float wt) {
    V8 nv; nv.u = *(const uint4*)(rowp + (size_t)ntok * 2304);
    #pragma unroll
    for (int j = 0; j < 8; ++j) acc[j] += wt * bf2f(nv.s[j]);
  };
  #pragma unroll
  for (int s = 1; s <= 3; ++s) {
    float ds = dist[s - 1];
    if (rank - 14 * s >= 0)  add(n - 14 * s, ds * w[(0 + (s - 1)) * 12 + h]);
    if (rank + 14 * s < 196) add(n + 14 * s, ds * w[(3 + (s - 1)) * 12 + h]);
    if (rw - s >= 0)         add(n - s,      ds * w[(6 + (s - 1)) * 12 + h]);
    if (rw + s <= 13)        add(n + s,      ds * w[(9 + (s - 1)) * 12 + h]);
  }
  V8 ov;
  #pragma unroll
  for (int j = 0; j < 8; ++j) ov.s[j] = f2bf(acc[j]);
  *(uint4*)(outp + rowoff_out) = ov.u;
}

// ---------------- fused attention: one block per (b,h), 8 waves ----------------
// q2/k2/v2: bf16 [B*H][197][64]; attn_o: bf16 [B][197][H*64]
// K and Q read from global (L1/L2-hot); V transposed in LDS; per-wave Pl buffer.
__global__ __launch_bounds__(512) void attn_kernel(
    const u16* __restrict__ q2, const u16* __restrict__ k2,
    const u16* __restrict__ v2, u16* __restrict__ attn_o) {
  __shared__ __align__(16) u16 Vt[64][232];
  __shared__ __align__(16) u16 Pl[8][16][40];
  int bh = blockIdx.x;
  int b = bh / 12, h = bh - b * 12;
  int tid = threadIdx.x, lane = tid & 63, wvid = tid >> 6;  // 8 waves
  int lq = lane & 15, oct = lane >> 4;
  const u16* kb_ = k2 + (size_t)bh * 197 * 64;
  const u16* vb_ = v2 + (size_t)bh * 197 * 64;
  const u16* qb_ = q2 + (size_t)bh * 197 * 64;

  auto process = [&](int rt, short8 qa0, short8 qa1) {
    f32x4 s[13];
    #pragma unroll
    for (int ct = 0; ct < 13; ++ct) {
      int krow = ct * 16 + lq; if (krow > 196) krow = 196;  // dup rows masked below
      short8 k0 = *(const short8*)(kb_ + (size_t)krow * 64 + oct * 8);
      short8 k1 = *(const short8*)(kb_ + (size_t)krow * 64 + 32 + oct * 8);
      f32x4 a = {0.f, 0.f, 0.f, 0.f};
      a = __builtin_amdgcn_mfma_f32_16x16x32_bf16(qa0, k0, a, 0, 0, 0);
      a = __builtin_amdgcn_mfma_f32_16x16x32_bf16(qa1, k1, a, 0, 0, 0);
      s[ct] = a;
    }
    float m[4] = {-3e38f, -3e38f, -3e38f, -3e38f};
    #pragma unroll
    for (int ct = 0; ct < 13; ++ct) {
      #pragma unroll
      for (int rr = 0; rr < 4; ++rr) {
        float v = s[ct][rr] * 0.125f;
        if (ct == 12 && lq >= 5) v = -1e30f;  // mask cols >= 197
        s[ct][rr] = v;
        m[rr] = fmaxf(m[rr], v);
      }
    }
    #pragma unroll
    for (int x = 1; x <= 8; x <<= 1) {
      #pragma unroll
      for (int rr = 0; rr < 4; ++rr) m[rr] = fmaxf(m[rr], __shfl_xor(m[rr], x, 64));
    }
    float rs[4] = {0.f, 0.f, 0.f, 0.f};
    #pragma unroll
    for (int ct = 0; ct < 13; ++ct) {
      #pragma unroll
      for (int rr = 0; rr < 4; ++rr) {
        float e = exp2f((s[ct][rr] - m[rr]) * 1.4426950408889634f);
        float er = bf2f(f2bf(e));  // quantize so f32 denominator matches bf16 P
        s[ct][rr] = er;
        rs[rr] += er;
      }
    }
    #pragma unroll
    for (int x = 1; x <= 8; x <<= 1) {
      #pragma unroll
      for (int rr = 0; rr < 4; ++rr) rs[rr] += __shfl_xor(rs[rr], x, 64);
    }
    f32x4 oacc[4];
    #pragma unroll
    for (int dt = 0; dt < 4; ++dt) oacc[dt] = (f32x4){0.f, 0.f, 0.f, 0.f};
    #pragma unroll
    for (int ks = 0; ks < 7; ++ks) {
      #pragma unroll
      for (int tt = 0; tt < 2; ++tt) {
        int ct = ks * 2 + tt;
        #pragma unroll
        for (int rr = 0; rr < 4; ++rr) {
          u16 pu = 0;
          if (ct < 13) pu = f2bf(s[ct < 13 ? ct : 0][rr]);
          Pl[wvid][oct * 4 + rr][tt * 16 + lq] = pu;
        }
      }
      short8 pa = *(const short8*)(&Pl[wvid][lq][oct * 8]);
      #pragma unroll
      for (int dt = 0; dt < 4; ++dt) {
        short8 vbf = *(const short8*)(&Vt[dt * 16 + lq][ks * 32 + oct * 8]);
        oacc[dt] = __builtin_amdgcn_mfma_f32_16x16x32_bf16(pa, vbf, oacc[dt], 0, 0, 0);
      }
    }
    #pragma unroll
    for (int dt = 0; dt < 4; ++dt) {
      #pragma unroll
      for (int rr = 0; rr < 4; ++rr) {
        int qr = rt * 16 + oct * 4 + rr;
        if (qr < 197) {
          float val = oacc[dt][rr] / rs[rr];
          attn_o[(((size_t)b * 197 + qr) * 12 + h) * 64 + dt * 16 + lq] = f2bf(val);
        }
      }
    }
  };

  // prefetch Q for first tile (issue before V staging so HBM latency hides)
  int rt0 = wvid;  // 0..7 < 13 always valid
  int qrow0 = rt0 * 16 + lq; if (qrow0 > 196) qrow0 = 196;
  short8 qa0 = *(const short8*)(qb_ + (size_t)qrow0 * 64 + oct * 8);
  short8 qa1 = *(const short8*)(qb_ + (size_t)qrow0 * 64 + 32 + oct * 8);

  // V staging (transposed), 512 threads
  for (int idx = tid; idx < 224 * 8; idx += 512) {
    int rrow = idx >> 3, dv = idx & 7;
    union { uint4 u; u16 s[8]; } val;
    val.u = make_uint4(0, 0, 0, 0);
    if (rrow < 197) val.u = *(const uint4*)(vb_ + (size_t)rrow * 64 + dv * 8);
    #pragma unroll
    for (int j = 0; j < 8; ++j) Vt[dv * 8 + j][rrow] = val.s[j];
  }
  __syncthreads();

  process(rt0, qa0, qa1);
  int rt1 = wvid + 8;
  if (rt1 < 13) {
    int qrow1 = rt1 * 16 + lq; if (qrow1 > 196) qrow1 = 196;
    short8 qb0 = *(const short8*)(qb_ + (size_t)qrow1 * 64 + oct * 8);
    short8 qb1 = *(const short8*)(qb_ + (size_t)qrow1 * 64 + 32 + oct * 8);
    process(rt1, qb0, qb1);
  }
}

extern "C" void kernel_launch(void* const* d_in, const int* in_sizes, int n_in,
                              void* d_out, int out_size, void* d_ws, size_t ws_size,
                              hipStream_t stream) {
  const float* x      = (const float*)d_in[0];
  const float* qkv_w  = (const float*)d_in[1];
  const float* qkv_b  = (const float*)d_in[2];
  const float* proj_w = (const float*)d_in[3];
  const float* proj_b = (const float*)d_in[4];
  const float* wq     = (const float*)d_in[5];
  const float* wk     = (const float*)d_in[6];
  const float* wv     = (const float*)d_in[7];
  float* out = (float*)d_out;

  // workspace layout (u16 units). SZ = 12608*768 = 768*197*64
  constexpr size_t SZ = 9682944;
  u16* ws = (u16*)d_ws;
  u16* xb   = ws;                    // x bf16 [12608][768]; later aliased as attn_o
  u16* wT   = xb + SZ;               // qkv_w^T bf16 [2304][768]
  u16* pT   = wT + 2304 * 768;       // proj_w^T bf16 [768][768]
  u16* qkvb = pT + 768 * 768;        // fused qkv bf16 [12608][2304]
  u16* q2   = qkvb + 3 * SZ;         // aggregated q/k/v [768][197][64]
  u16* k2   = q2 + SZ;
  u16* v2   = k2 + SZ;
  u16* ao   = xb;                    // attn output aliases xb (dead after QKV GEMM)

  convert_f32_bf16<<<dim3(9456), dim3(256), 0, stream>>>(x, xb, 2420736);
  transpose_f32_bf16<<<dim3(72, 24), dim3(32, 8), 0, stream>>>(qkv_w, wT, 768, 2304);
  transpose_f32_bf16<<<dim3(24, 24), dim3(32, 8), 0, stream>>>(proj_w, pT, 768, 768);
  gemm_gll<0><<<dim3(99 * 18), dim3(256), 0, stream>>>(xb, wT, 12608, 18, qkv_b, qkvb, nullptr);
  save_agg_fused<<<dim3(14184), dim3(256), 0, stream>>>(qkvb, q2, k2, v2, wq, wk, wv);
  attn_kernel<<<dim3(768), dim3(512), 0, stream>>>(q2, k2, v2, ao);
  gemm_gll<1><<<dim3(99 * 6), dim3(256), 0, stream>>>(ao, pT, 12608, 6, proj_b, nullptr, out);
}

// Round 8
// 298.038 us; speedup vs baseline: 1.0654x; 1.0654x over previous
//
#include <hip/hip_runtime.h>

typedef unsigned short u16;
typedef __attribute__((ext_vector_type(8))) short short8;
typedef __attribute__((ext_vector_type(4))) float f32x4;

__device__ __forceinline__ u16 f2bf(float f) {
  unsigned u = __builtin_bit_cast(unsigned, f);
  u += 0x7FFFu + ((u >> 16) & 1u);
  return (u16)(u >> 16);
}
__device__ __forceinline__ float bf2f(u16 s) {
  unsigned u = ((unsigned)s) << 16;
  return __builtin_bit_cast(float, u);
}
__device__ __forceinline__ void gll16(const u16* g, u16* l) {
  __builtin_amdgcn_global_load_lds(
      (const __attribute__((address_space(1))) void*)g,
      (__attribute__((address_space(3))) void*)l, 16, 0, 0);
}

// ---------------- convert f32 -> bf16 (vectorized) ----------------
__global__ __launch_bounds__(256) void convert_f32_bf16(
    const float* __restrict__ in, u16* __restrict__ out, int n4) {
  int i = blockIdx.x * 256 + threadIdx.x;
  if (i >= n4) return;
  float4 v = ((const float4*)in)[i];
  ushort4 o;
  o.x = f2bf(v.x); o.y = f2bf(v.y); o.z = f2bf(v.z); o.w = f2bf(v.w);
  ((ushort4*)out)[i] = o;
}

// ---------------- transpose f32[R][C] -> bf16[C][R] ----------------
__global__ __launch_bounds__(256) void transpose_f32_bf16(
    const float* __restrict__ in, u16* __restrict__ out, int R, int C) {
  __shared__ float tile[32][33];
  int c0 = blockIdx.x * 32, r0 = blockIdx.y * 32;
  int tx = threadIdx.x, ty = threadIdx.y;
  #pragma unroll
  for (int i = 0; i < 32; i += 8)
    tile[ty + i][tx] = in[(size_t)(r0 + ty + i) * C + c0 + tx];
  __syncthreads();
  #pragma unroll
  for (int i = 0; i < 32; i += 8)
    out[(size_t)(c0 + ty + i) * R + r0 + tx] = f2bf(tile[tx][ty + i]);
}

// ---------------- 128x128 bf16 MFMA GEMM, BK=64, swizzled LDS ----------------
// LDS dest linear (global_load_lds requirement); global SOURCE slot pre-permuted;
// ds_read applies the same XOR (rule #21). BANK_CONFLICT measured 0 (R7).
template<int MODE>
__global__ __launch_bounds__(256) void gemm_gll(
    const u16* __restrict__ A, const u16* __restrict__ Bt, int M, int NT,
    const float* __restrict__ bias, u16* __restrict__ ob, float* __restrict__ of) {
  constexpr int K = 768;
  __shared__ __align__(16) u16 Al[128 * 64];
  __shared__ __align__(16) u16 Bl[128 * 64];
  int tid = threadIdx.x, lane = tid & 63, w = tid >> 6;
  int nwg = gridDim.x, orig = blockIdx.x;
  int q = nwg >> 3, r = nwg & 7, xcd = orig & 7, slot = orig >> 3;
  int wg = (xcd < r ? xcd * (q + 1) : r * (q + 1) + (xcd - r) * q) + slot;
  int mt = wg / NT, nt = wg - mt * NT;
  int m0 = mt * 128, n0 = nt * 128;
  int wm = w >> 1, wn = w & 1;
  int lq = lane & 15, oct = lane >> 4;
  int srow = w * 8 + (lane >> 3);
  int sslot = (lane & 7) ^ (lane >> 3);
  const u16* gA[4];
  const u16* gB[4];
  #pragma unroll
  for (int p = 0; p < 4; ++p) {
    int ar = m0 + p * 32 + srow; if (ar > M - 1) ar = M - 1;
    gA[p] = A + (size_t)ar * K + sslot * 8;
    gB[p] = Bt + (size_t)(n0 + p * 32 + srow) * K + sslot * 8;
  }
  f32x4 acc[4][4] = {};
  for (int kt = 0; kt < K; kt += 64) {
    #pragma unroll
    for (int p = 0; p < 4; ++p) {
      gll16(gA[p] + kt, Al + p * 2048 + w * 512);
      gll16(gB[p] + kt, Bl + p * 2048 + w * 512);
    }
    __syncthreads();   // vmcnt(0) drain + barrier
    #pragma unroll
    for (int ks = 0; ks < 2; ++ks) {
      short8 af[4], bq[4];
      int rslot = ((ks * 4 + oct) ^ (lq & 7)) * 8;
      #pragma unroll
      for (int i = 0; i < 4; ++i)
        af[i] = *(const short8*)(Al + (wm * 64 + i * 16 + lq) * 64 + rslot);
      #pragma unroll
      for (int j = 0; j < 4; ++j)
        bq[j] = *(const short8*)(Bl + (wn * 64 + j * 16 + lq) * 64 + rslot);
      #pragma unroll
      for (int i = 0; i < 4; ++i)
        #pragma unroll
        for (int j = 0; j < 4; ++j)
          acc[i][j] = __builtin_amdgcn_mfma_f32_16x16x32_bf16(af[i], bq[j], acc[i][j], 0, 0, 0);
    }
    __syncthreads();   // protect LDS before next stage
  }
  int ldc = NT * 128;
  float bs[4];
  #pragma unroll
  for (int j = 0; j < 4; ++j) bs[j] = bias[n0 + wn * 64 + j * 16 + lq];
  #pragma unroll
  for (int i = 0; i < 4; ++i) {
    #pragma unroll
    for (int rr = 0; rr < 4; ++rr) {
      int m = m0 + wm * 64 + i * 16 + oct * 4 + rr;
      if (m < M) {
        #pragma unroll
        for (int j = 0; j < 4; ++j) {
          int c = n0 + wn * 64 + j * 16 + lq;
          float val = acc[i][j][rr] + bs[j];
          if (MODE == 0) ob[(size_t)m * ldc + c] = f2bf(val);
          else           of[(size_t)m * ldc + c] = val;
        }
      }
    }
  }
}

// ---------------- SAVE aggregation, fused q/k/v, 32B per thread ----------------
// in: bf16 [B*197][2304]; out: q2/k2/v2 [B*H][197][64]. Each thread: 2 chunks.
__global__ __launch_bounds__(256) void save_agg_fused(
    const u16* __restrict__ in, u16* __restrict__ q2, u16* __restrict__ k2,
    u16* __restrict__ v2, const float* __restrict__ wq,
    const float* __restrict__ wk, const float* __restrict__ wv) {
  constexpr int PER = 768 * 197 * 4;  // per-tensor 32B chunks
  int vid = blockIdx.x * 256 + threadIdx.x;
  if (vid >= 3 * PER) return;
  int which = vid / PER;
  int rem = vid - which * PER;
  int dv = rem & 3;                  // 32B chunk: elems dv*16 .. dv*16+15
  int n = (rem >> 2) % 197;
  int bh = rem / (197 * 4);
  int b = bh / 12, h = bh - b * 12;
  const float* w = (which == 0) ? wq : (which == 1) ? wk : wv;
  u16* outp = (which == 0) ? q2 : (which == 1) ? k2 : v2;
  size_t colbase = (size_t)which * 768 + h * 64 + dv * 16;
  const u16* rowp = in + (size_t)b * 197 * 2304 + colbase;
  u16* outrow = outp + ((size_t)bh * 197 + n) * 64 + dv * 16;
  union V16 { uint4 u[2]; u16 s[16]; };
  V16 cv;
  cv.u[0] = *(const uint4*)(rowp + (size_t)n * 2304);
  cv.u[1] = *(const uint4*)(rowp + (size_t)n * 2304 + 8);
  if (n == 0) {
    *(uint4*)(outrow) = cv.u[0];
    *(uint4*)(outrow + 8) = cv.u[1];
    return;
  }
  float acc[16];
  #pragma unroll
  for (int j = 0; j < 16; ++j) acc[j] = bf2f(cv.s[j]);
  int rank = n - 1;
  int rw = rank % 14;
  const float dist[3] = {0.93941306281347579f, 0.77880078307140487f, 0.56978282473092302f};
  auto add = [&](int ntok, float wt) {
    V16 nv;
    nv.u[0] = *(const uint4*)(rowp + (size_t)ntok * 2304);
    nv.u[1] = *(const uint4*)(rowp + (size_t)ntok * 2304 + 8);
    #pragma unroll
    for (int j = 0; j < 16; ++j) acc[j] += wt * bf2f(nv.s[j]);
  };
  #pragma unroll
  for (int s = 1; s <= 3; ++s) {
    float ds = dist[s - 1];
    if (rank - 14 * s >= 0)  add(n - 14 * s, ds * w[(0 + (s - 1)) * 12 + h]);
    if (rank + 14 * s < 196) add(n + 14 * s, ds * w[(3 + (s - 1)) * 12 + h]);
    if (rw - s >= 0)         add(n - s,      ds * w[(6 + (s - 1)) * 12 + h]);
    if (rw + s <= 13)        add(n + s,      ds * w[(9 + (s - 1)) * 12 + h]);
  }
  V16 ov;
  #pragma unroll
  for (int j = 0; j < 16; ++j) ov.s[j] = f2bf(acc[j]);
  *(uint4*)(outrow) = ov.u[0];
  *(uint4*)(outrow + 8) = ov.u[1];
}

// ---------------- fused attention: one block per (b,h), 4 waves (R4 proven) ----------------
// q2/k2/v2: bf16 [B*H][197][64]; attn_o: bf16 [B][197][H*64]
// K and Q read from global (L1/L2-hot); V transposed in LDS; per-wave Pl buffer.
__global__ __launch_bounds__(256) void attn_kernel(
    const u16* __restrict__ q2, const u16* __restrict__ k2,
    const u16* __restrict__ v2, u16* __restrict__ attn_o) {
  __shared__ __align__(16) u16 Vt[64][232];
  __shared__ __align__(16) u16 Pl[4][16][40];
  int bh = blockIdx.x;
  int b = bh / 12, h = bh - b * 12;
  int tid = threadIdx.x, lane = tid & 63, wvid = tid >> 6;
  int lq = lane & 15, oct = lane >> 4;
  const u16* kb_ = k2 + (size_t)bh * 197 * 64;
  const u16* vb_ = v2 + (size_t)bh * 197 * 64;
  const u16* qb_ = q2 + (size_t)bh * 197 * 64;

  for (int idx = tid; idx < 224 * 8; idx += 256) {
    int r = idx >> 3, dv = idx & 7;
    union { uint4 u; u16 s[8]; } val;
    val.u = make_uint4(0, 0, 0, 0);
    if (r < 197) val.u = *(const uint4*)(vb_ + (size_t)r * 64 + dv * 8);
    #pragma unroll
    for (int j = 0; j < 8; ++j) Vt[dv * 8 + j][r] = val.s[j];
  }
  __syncthreads();

  for (int rt = wvid; rt < 13; rt += 4) {
    int qrow = rt * 16 + lq; if (qrow > 196) qrow = 196;
    short8 qa0 = *(const short8*)(qb_ + (size_t)qrow * 64 + oct * 8);
    short8 qa1 = *(const short8*)(qb_ + (size_t)qrow * 64 + 32 + oct * 8);
    f32x4 s[13];
    #pragma unroll
    for (int ct = 0; ct < 13; ++ct) {
      int krow = ct * 16 + lq; if (krow > 196) krow = 196;  // dup rows masked below
      short8 k0 = *(const short8*)(kb_ + (size_t)krow * 64 + oct * 8);
      short8 k1 = *(const short8*)(kb_ + (size_t)krow * 64 + 32 + oct * 8);
      f32x4 a = {0.f, 0.f, 0.f, 0.f};
      a = __builtin_amdgcn_mfma_f32_16x16x32_bf16(qa0, k0, a, 0, 0, 0);
      a = __builtin_amdgcn_mfma_f32_16x16x32_bf16(qa1, k1, a, 0, 0, 0);
      s[ct] = a;
    }
    float m[4] = {-3e38f, -3e38f, -3e38f, -3e38f};
    #pragma unroll
    for (int ct = 0; ct < 13; ++ct) {
      #pragma unroll
      for (int rr = 0; rr < 4; ++rr) {
        float v = s[ct][rr] * 0.125f;
        if (ct == 12 && lq >= 5) v = -1e30f;  // mask cols >= 197
        s[ct][rr] = v;
        m[rr] = fmaxf(m[rr], v);
      }
    }
    #pragma unroll
    for (int x = 1; x <= 8; x <<= 1) {
      #pragma unroll
      for (int rr = 0; rr < 4; ++rr) m[rr] = fmaxf(m[rr], __shfl_xor(m[rr], x, 64));
    }
    float rs[4] = {0.f, 0.f, 0.f, 0.f};
    #pragma unroll
    for (int ct = 0; ct < 13; ++ct) {
      #pragma unroll
      for (int rr = 0; rr < 4; ++rr) {
        float e = exp2f((s[ct][rr] - m[rr]) * 1.4426950408889634f);
        float er = bf2f(f2bf(e));  // quantize so f32 denominator matches bf16 P
        s[ct][rr] = er;
        rs[rr] += er;
      }
    }
    #pragma unroll
    for (int x = 1; x <= 8; x <<= 1) {
      #pragma unroll
      for (int rr = 0; rr < 4; ++rr) rs[rr] += __shfl_xor(rs[rr], x, 64);
    }
    f32x4 oacc[4];
    #pragma unroll
    for (int dt = 0; dt < 4; ++dt) oacc[dt] = (f32x4){0.f, 0.f, 0.f, 0.f};
    #pragma unroll
    for (int ks = 0; ks < 7; ++ks) {
      #pragma unroll
      for (int tt = 0; tt < 2; ++tt) {
        int ct = ks * 2 + tt;
        #pragma unroll
        for (int rr = 0; rr < 4; ++rr) {
          u16 pu = 0;
          if (ct < 13) pu = f2bf(s[ct < 13 ? ct : 0][rr]);
          Pl[wvid][oct * 4 + rr][tt * 16 + lq] = pu;
        }
      }
      short8 pa = *(const short8*)(&Pl[wvid][lq][oct * 8]);
      #pragma unroll
      for (int dt = 0; dt < 4; ++dt) {
        short8 vbf = *(const short8*)(&Vt[dt * 16 + lq][ks * 32 + oct * 8]);
        oacc[dt] = __builtin_amdgcn_mfma_f32_16x16x32_bf16(pa, vbf, oacc[dt], 0, 0, 0);
      }
    }
    #pragma unroll
    for (int dt = 0; dt < 4; ++dt) {
      #pragma unroll
      for (int rr = 0; rr < 4; ++rr) {
        int qr = rt * 16 + oct * 4 + rr;
        if (qr < 197) {
          float val = oacc[dt][rr] / rs[rr];
          attn_o[(((size_t)b * 197 + qr) * 12 + h) * 64 + dt * 16 + lq] = f2bf(val);
        }
      }
    }
  }
}

extern "C" void kernel_launch(void* const* d_in, const int* in_sizes, int n_in,
                              void* d_out, int out_size, void* d_ws, size_t ws_size,
                              hipStream_t stream) {
  const float* x      = (const float*)d_in[0];
  const float* qkv_w  = (const float*)d_in[1];
  const float* qkv_b  = (const float*)d_in[2];
  const float* proj_w = (const float*)d_in[3];
  const float* proj_b = (const float*)d_in[4];
  const float* wq     = (const float*)d_in[5];
  const float* wk     = (const float*)d_in[6];
  const float* wv     = (const float*)d_in[7];
  float* out = (float*)d_out;

  // workspace layout (u16 units). SZ = 12608*768 = 768*197*64
  constexpr size_t SZ = 9682944;
  u16* ws = (u16*)d_ws;
  u16* xb   = ws;                    // x bf16 [12608][768]; later aliased as attn_o
  u16* wT   = xb + SZ;               // qkv_w^T bf16 [2304][768]
  u16* pT   = wT + 2304 * 768;       // proj_w^T bf16 [768][768]
  u16* qkvb = pT + 768 * 768;        // fused qkv bf16 [12608][2304]
  u16* q2   = qkvb + 3 * SZ;         // aggregated q/k/v [768][197][64]
  u16* k2   = q2 + SZ;
  u16* v2   = k2 + SZ;
  u16* ao   = xb;                    // attn output aliases xb (dead after QKV GEMM)

  convert_f32_bf16<<<dim3(9456), dim3(256), 0, stream>>>(x, xb, 2420736);
  transpose_f32_bf16<<<dim3(72, 24), dim3(32, 8), 0, stream>>>(qkv_w, wT, 768, 2304);
  transpose_f32_bf16<<<dim3(24, 24), dim3(32, 8), 0, stream>>>(proj_w, pT, 768, 768);
  gemm_gll<0><<<dim3(99 * 18), dim3(256), 0, stream>>>(xb, wT, 12608, 18, qkv_b, qkvb, nullptr);
  save_agg_fused<<<dim3(7092), dim3(256), 0, stream>>>(qkvb, q2, k2, v2, wq, wk, wv);
  attn_kernel<<<dim3(768), dim3(256), 0, stream>>>(q2, k2, v2, ao);
  gemm_gll<1><<<dim3(99 * 6), dim3(256), 0, stream>>>(ao, pT, 12608, 6, proj_b, nullptr, out);
}